// Round 2
// baseline (1621.667 us; speedup 1.0000x reference)
//
#include <hip/hip_runtime.h>
#include <math.h>

// ---------------------------------------------------------------------------
// RecurrentEncoder: LSTM (B=256, D=2048, H=2048, T=32) + emission head (K=64)
// Round 5: persistent tick loop with HAND-ROLLED grid barrier (plain launch;
// no hipLaunchCooperativeKernel -> graph-capture-safe). W_hh slab (128 KB =
// 32 cols x K2048 bf16) loaded into LDS ONCE per block, resident across all
// 32 ticks. 256 blocks x 512 thr, 128 KB LDS => exactly 1 block/CU => all
// blocks co-resident by capacity, so the device-scope barrier cannot deadlock.
// A (h^T) streams global->register depth-8 ring; xg prefetched per tick.
// ---------------------------------------------------------------------------

typedef short  short8  __attribute__((ext_vector_type(8)));   // 8 x bf16
typedef float  floatx4 __attribute__((ext_vector_type(4)));

#define BB 256
#define HH 2048
#define G4 8192
#define KK 64
#define TT 32

__device__ __forceinline__ unsigned short f2bf(float f) {
  union { float f; unsigned int u; } v; v.f = f;
  unsigned int u = v.u;
  u += 0x7fffu + ((u >> 16) & 1u);   // round-to-nearest-even
  return (unsigned short)(u >> 16);
}
__device__ __forceinline__ float sigmoidf_(float x) { return 1.0f / (1.0f + __expf(-x)); }
__device__ __forceinline__ float softplusf_(float x) {
  return (x > 20.0f) ? x : log1pf(__expf(x));
}
__device__ __forceinline__ short8 cvt8(const float* __restrict__ s) {
  float4 a = reinterpret_cast<const float4*>(s)[0];
  float4 b = reinterpret_cast<const float4*>(s)[1];
  short8 o;
  o[0] = f2bf(a.x); o[1] = f2bf(a.y); o[2] = f2bf(a.z); o[3] = f2bf(a.w);
  o[4] = f2bf(b.x); o[5] = f2bf(b.y); o[6] = f2bf(b.z); o[7] = f2bf(b.w);
  return o;
}

// ---------------------------------------------------------------------------
// Weight transform: fp32 row-major [q or gate-major][K] ->
// bf16 chunks [blk][phase 2][k8 128][col 32][8elem]  (exact LDS slab layout).
// PERM=1: q = u*4+g  ->  src row g*2048+u  (LSTM gate interleave).
// ---------------------------------------------------------------------------
template <int PERM>
__global__ void cvt_w_kernel(const float* __restrict__ in,
                             unsigned short* __restrict__ out, int total) {
  int tid = blockIdx.x * 256 + threadIdx.x;
  if (tid >= total) return;
  int col = tid & 31;
  int k4  = (tid >> 5) & 63;    // pair index: k8 = 2*k4
  int ph  = (tid >> 11) & 1;
  int blk = tid >> 12;
  int q = blk * 32 + col;
  int srcrow = PERM ? ((q & 3) * HH + (q >> 2)) : q;
  const float* src = in + (size_t)srcrow * HH + (ph * 128 + k4 * 2) * 8;
  short8 o0 = cvt8(src);
  short8 o1 = cvt8(src + 8);
  size_t ch = ((size_t)(blk * 2 + ph) * 128 + k4 * 2) * 32 + col;
  reinterpret_cast<short8*>(out)[ch]      = o0;
  reinterpret_cast<short8*>(out)[ch + 32] = o1;
}

// x fp32 [256][2048] -> x^T chunks [k8 256][row 256][8]
__global__ void cvt_x_kernel(const float* __restrict__ in,
                             unsigned short* __restrict__ out) {
  int tid = blockIdx.x * 256 + threadIdx.x;   // 65536
  int row = tid & 255, k8 = tid >> 8;
  short8 o = cvt8(in + (size_t)row * HH + k8 * 8);
  reinterpret_cast<short8*>(out)[tid] = o;    // chunk = k8*256 + row
}

// ---------------------------------------------------------------------------
// Core GEMM (used by xg / fe): 256 rows x 32 cols x K2048. W staged via LDS
// in two 64 KB phases; A ring-prefetched depth 4.
// ---------------------------------------------------------------------------
__device__ __forceinline__ void core_gemm(const short8* __restrict__ A8,
                                          const short8* __restrict__ Wg8,
                                          short8* L8, floatx4 acc[2][2]) {
  const int tid = threadIdx.x;
  const int lane = tid & 63, wave = tid >> 6;
  const int l15 = lane & 15, l4 = lane >> 4;
  const short8* Lr = L8 + l4 * 32 + l15;          // + kt*128 + ct*16
  const int abase = l4 * 256 + wave * 32 + l15;   // chunk = k8*256 + row (+rt*16)
  for (int ph = 0; ph < 2; ++ph) {
    __syncthreads();   // protect slab from previous phase's readers
#pragma unroll
    for (int j = 0; j < 8; ++j)
      L8[tid + j * 512] = Wg8[ph * 4096 + tid + j * 512];
    __syncthreads();
    short8 Ar[4][2];
#pragma unroll
    for (int i = 0; i < 4; ++i) {
      Ar[i][0] = A8[abase +      (ph * 128 + i * 4) * 256];
      Ar[i][1] = A8[abase + 16 + (ph * 128 + i * 4) * 256];
    }
#pragma unroll
    for (int kt = 0; kt < 32; ++kt) {
      short8 a0 = Ar[kt & 3][0], a1 = Ar[kt & 3][1];
      if (kt < 28) {
        Ar[kt & 3][0] = A8[abase +      (ph * 128 + (kt + 4) * 4) * 256];
        Ar[kt & 3][1] = A8[abase + 16 + (ph * 128 + (kt + 4) * 4) * 256];
      }
      short8 b0 = Lr[kt * 128];
      short8 b1 = Lr[kt * 128 + 16];
      acc[0][0] = __builtin_amdgcn_mfma_f32_16x16x32_bf16(a0, b0, acc[0][0], 0, 0, 0);
      acc[0][1] = __builtin_amdgcn_mfma_f32_16x16x32_bf16(a0, b1, acc[0][1], 0, 0, 0);
      acc[1][0] = __builtin_amdgcn_mfma_f32_16x16x32_bf16(a1, b0, acc[1][0], 0, 0, 0);
      acc[1][1] = __builtin_amdgcn_mfma_f32_16x16x32_bf16(a1, b1, acc[1][1], 0, 0, 0);
    }
  }
}

// ---------------------------------------------------------------------------
// Persistent LSTM loop. 256 blocks x 512 threads, plain launch. 128 KB W slab
// resident in LDS for all 32 ticks. Block owns q-cols [32b, 32b+32) =
// units [8b, 8b+8) x 4 gates. Per tick: depth-8 A ring -> 256x32 GEMM ->
// gate epilogue -> h^T write -> device-scope grid barrier.
// Barrier soundness: __syncthreads drains every wave's vmcnt (stores in L2);
// thread-0 agent-scope RELEASE fetch-add writes L2 back (cross-XCD visible);
// thread-0 agent-scope ACQUIRE spin invalidates caches; __syncthreads holds
// the block. Counter is monotonic (target (t+1)*256), memset to 0 per launch.
// ---------------------------------------------------------------------------
__global__ __launch_bounds__(512) void lstm_loop_kernel(
    unsigned short* __restrict__ HallT, const unsigned short* __restrict__ Wt2,
    const float* __restrict__ xg, float* __restrict__ c,
    float* __restrict__ outh, float* __restrict__ outc,
    unsigned int* __restrict__ bar) {
  __shared__ __align__(16) unsigned short Wlds[65536];   // 128 KB
  const int tid = threadIdx.x;
  short8* L8 = reinterpret_cast<short8*>(Wlds);
  {
    const short8* Wg8 = reinterpret_cast<const short8*>(Wt2)
                        + (size_t)blockIdx.x * 8192;
#pragma unroll
    for (int j = 0; j < 16; ++j)
      L8[tid + j * 512] = Wg8[tid + j * 512];
  }
  __syncthreads();

  const int lane = tid & 63, wave = tid >> 6;
  const int l15 = lane & 15, l4 = lane >> 4;
  const short8* Lr = L8 + l4 * 32 + l15;          // + kt*128 + ct*16
  const int abase = l4 * 256 + wave * 32 + l15;   // chunk = k8*256 + row (+rt*16)
  const int qb = blockIdx.x * 32, rw = wave * 32;
  const int gate = l15 & 3;
  const int base = lane & ~3;

#pragma unroll 1
  for (int t = 0; t < TT; ++t) {
    const short8* A8 = reinterpret_cast<const short8*>(HallT) + (size_t)t * 65536;
    unsigned short* Hout = HallT + (size_t)(t + 1) * 524288;

    // Prefetch epilogue operands early (hide under the K loop).
    float xgr[2][2][4];
#pragma unroll
    for (int rt = 0; rt < 2; ++rt)
#pragma unroll
      for (int ct = 0; ct < 2; ++ct) {
        const int q = qb + ct * 16 + l15;
#pragma unroll
        for (int r = 0; r < 4; ++r) {
          const int row = rw + rt * 16 + l4 * 4 + r;
          xgr[rt][ct][r] = xg[(size_t)row * G4 + q];
        }
      }

    floatx4 acc[2][2];
    floatx4 z4 = {0.f, 0.f, 0.f, 0.f};
    acc[0][0] = z4; acc[0][1] = z4; acc[1][0] = z4; acc[1][1] = z4;

    // Depth-8 A ring over the merged K loop (64 kt steps, W LDS-resident).
    short8 Ar[8][2];
#pragma unroll
    for (int i = 0; i < 8; ++i) {
      Ar[i][0] = A8[abase +      i * 1024];
      Ar[i][1] = A8[abase + 16 + i * 1024];
    }
#pragma unroll
    for (int kt = 0; kt < 64; ++kt) {
      short8 a0 = Ar[kt & 7][0], a1 = Ar[kt & 7][1];
      if (kt < 56) {
        Ar[kt & 7][0] = A8[abase +      (kt + 8) * 1024];
        Ar[kt & 7][1] = A8[abase + 16 + (kt + 8) * 1024];
      }
      short8 b0 = Lr[kt * 128];
      short8 b1 = Lr[kt * 128 + 16];
      acc[0][0] = __builtin_amdgcn_mfma_f32_16x16x32_bf16(a0, b0, acc[0][0], 0, 0, 0);
      acc[0][1] = __builtin_amdgcn_mfma_f32_16x16x32_bf16(a0, b1, acc[0][1], 0, 0, 0);
      acc[1][0] = __builtin_amdgcn_mfma_f32_16x16x32_bf16(a1, b0, acc[1][0], 0, 0, 0);
      acc[1][1] = __builtin_amdgcn_mfma_f32_16x16x32_bf16(a1, b1, acc[1][1], 0, 0, 0);
    }

    const int last = (t == TT - 1);
#pragma unroll
    for (int rt = 0; rt < 2; ++rt)
#pragma unroll
      for (int ct = 0; ct < 2; ++ct) {
        const floatx4 av = acc[rt][ct];
        const int q = qb + ct * 16 + l15;
        const int u = q >> 2;
#pragma unroll
        for (int r = 0; r < 4; ++r) {
          const int row = rw + rt * 16 + l4 * 4 + r;
          float g = av[r] + xgr[rt][ct][r];
          float act = (gate == 2) ? tanhf(g) : sigmoidf_(g);
          float iv = __shfl(act, base);
          float fv = __shfl(act, base + 1);
          float gv = __shfl(act, base + 2);
          float ov = __shfl(act, base + 3);
          if (gate == 0) {
            const size_t ci = (size_t)row * HH + u;
            float cnew = fv * c[ci] + iv * gv;
            float hnew = ov * tanhf(cnew);
            c[ci] = cnew;
            Hout[(size_t)(blockIdx.x * 256 + row) * 8 + (u & 7)] = f2bf(hnew);
            if (last) { outh[ci] = hnew; outc[ci] = cnew; }
          }
        }
      }

    if (t < TT - 1) {
      // ---- device-scope grid barrier (all 256 blocks resident, 1/CU) ----
      __syncthreads();   // drains vmcnt(0): all waves' h/c stores are in L2
      if (tid == 0) {
        __hip_atomic_fetch_add(bar, 1u, __ATOMIC_RELEASE,
                               __HIP_MEMORY_SCOPE_AGENT);
        const unsigned int target = (unsigned int)(t + 1) * 256u;
        while (__hip_atomic_load(bar, __ATOMIC_ACQUIRE,
                                 __HIP_MEMORY_SCOPE_AGENT) < target)
          __builtin_amdgcn_s_sleep(2);
      }
      __syncthreads();
    }
  }
}

// xg = x @ W_ih^T (q-permuted cols) + b_ih + b_hh
__global__ __launch_bounds__(512) void xg_kernel(
    const unsigned short* __restrict__ XT, const unsigned short* __restrict__ Wih,
    const float* __restrict__ b_ih, const float* __restrict__ b_hh,
    float* __restrict__ xg) {
  __shared__ __align__(16) unsigned short Wlds[32768];
  floatx4 acc[2][2];
  floatx4 z4 = {0.f, 0.f, 0.f, 0.f};
  acc[0][0] = z4; acc[0][1] = z4; acc[1][0] = z4; acc[1][1] = z4;
  core_gemm(reinterpret_cast<const short8*>(XT),
            reinterpret_cast<const short8*>(Wih) + (size_t)blockIdx.x * 8192,
            reinterpret_cast<short8*>(Wlds), acc);

  const int tid = threadIdx.x, lane = tid & 63, wave = tid >> 6;
  const int l15 = lane & 15, l4 = lane >> 4;
  const int qb = blockIdx.x * 32, rw = wave * 32;
#pragma unroll
  for (int rt = 0; rt < 2; ++rt)
#pragma unroll
    for (int ct = 0; ct < 2; ++ct) {
      const int q = qb + ct * 16 + l15;
      const float bias = b_ih[(q & 3) * HH + (q >> 2)] + b_hh[(q & 3) * HH + (q >> 2)];
#pragma unroll
      for (int r = 0; r < 4; ++r) {
        const int row = rw + rt * 16 + l4 * 4 + r;
        xg[(size_t)row * G4 + q] = acc[rt][ct][r] + bias;
      }
    }
}

// fe = h_t @ W_fe^T + b_fe for all t: block = (t, colgroup of 32)
__global__ __launch_bounds__(512) void fe_kernel(
    const unsigned short* __restrict__ HallT, const unsigned short* __restrict__ Wfe,
    const float* __restrict__ b_fe, float* __restrict__ fe) {
  const int t = blockIdx.x >> 2, cg_ = blockIdx.x & 3;
  __shared__ __align__(16) unsigned short Wlds[32768];
  floatx4 acc[2][2];
  floatx4 z4 = {0.f, 0.f, 0.f, 0.f};
  acc[0][0] = z4; acc[0][1] = z4; acc[1][0] = z4; acc[1][1] = z4;
  core_gemm(reinterpret_cast<const short8*>(HallT) + (size_t)(t + 1) * 65536,
            reinterpret_cast<const short8*>(Wfe) + (size_t)cg_ * 8192,
            reinterpret_cast<short8*>(Wlds), acc);

  const int tid = threadIdx.x, lane = tid & 63, wave = tid >> 6;
  const int l15 = lane & 15, l4 = lane >> 4;
  const int rw = wave * 32;
#pragma unroll
  for (int rt = 0; rt < 2; ++rt)
#pragma unroll
    for (int ct = 0; ct < 2; ++ct) {
      const int col = cg_ * 32 + ct * 16 + l15;
      const float bias = b_fe[col];
#pragma unroll
      for (int r = 0; r < 4; ++r) {
        const int row = rw + rt * 16 + l4 * 4 + r;
        fe[((size_t)t * 256 + row) * 128 + col] = acc[rt][ct][r] + bias;
      }
    }
}

// z = eps*softplus(fe[:,64:]-5) + fe[:,:64]; outputs laid out (B,K,T)
__global__ void z_kernel(const float* __restrict__ eps, const float* __restrict__ fe,
                         float* __restrict__ out) {
  const int tid = blockIdx.x * blockDim.x + threadIdx.x;  // 524288 = T*B*K
  const int tt = tid >> 14;
  const int b = (tid >> 6) & 255;
  const int k = tid & 63;
  const int frow = tt * 256 + b;
  const float mus = fe[frow * 128 + k];
  const float sig = softplusf_(fe[frow * 128 + 64 + k] - 5.0f);
  const float z = eps[tid] * sig + mus;
  const int o = (b * KK + k) * TT + tt;
  out[o] = z;
  out[524288 + o] = mus;
  out[2 * 524288 + o] = sig;
}

extern "C" void kernel_launch(void* const* d_in, const int* in_sizes, int n_in,
                              void* d_out, int out_size, void* d_ws, size_t ws_size,
                              hipStream_t stream) {
  const float* x    = (const float*)d_in[0];
  const float* eps  = (const float*)d_in[1];
  const float* W_ih = (const float*)d_in[2];
  const float* W_hh = (const float*)d_in[3];
  const float* b_ih = (const float*)d_in[4];
  const float* b_hh = (const float*)d_in[5];
  const float* W_fe = (const float*)d_in[6];
  const float* b_fe = (const float*)d_in[7];
  float* out = (float*)d_out;

  const size_t BH  = (size_t)BB * HH;       // 524288
  const size_t BKT = (size_t)BB * KK * TT;  // 524288

  char* p = (char*)d_ws;
  auto nxt = [&](size_t bytes) -> char* {
    char* r = p; p += (bytes + 255) & ~(size_t)255; return r;
  };
  unsigned short* Wbig  = (unsigned short*)nxt((size_t)G4 * HH * 2);       // 32 MB, W_ih then W_hh
  float*          xg    = (float*)nxt((size_t)BB * G4 * 4);                // 8 MB
  float*          c     = (float*)nxt(BH * 4);                             // 2 MB
  unsigned short* HallT = (unsigned short*)nxt((size_t)(TT + 1) * BH * 2); // 33 MB
  unsigned short* XT    = (unsigned short*)nxt(BH * 2);                    // 1 MB
  unsigned short* Wfeb  = (unsigned short*)nxt((size_t)128 * HH * 2);      // 0.5 MB
  float*          fe    = (float*)nxt((size_t)(TT * BB) * 128 * 4);        // 4 MB
  unsigned int*   bar   = (unsigned int*)nxt(256);                         // grid barrier

  hipMemsetAsync(c, 0, BH * 4, stream);
  hipMemsetAsync(HallT, 0, BH * 2, stream);  // slot 0 = h0 = 0
  hipMemsetAsync(bar, 0, 256, stream);

  cvt_x_kernel<<<256, 256, 0, stream>>>(x, XT);
  cvt_w_kernel<0><<<64, 256, 0, stream>>>(W_fe, Wfeb, 16384);
  cvt_w_kernel<1><<<4096, 256, 0, stream>>>(W_ih, Wbig, 1048576);
  xg_kernel<<<256, 512, 0, stream>>>(XT, Wbig, b_ih, b_hh, xg);
  cvt_w_kernel<1><<<4096, 256, 0, stream>>>(W_hh, Wbig, 1048576);

  lstm_loop_kernel<<<256, 512, 0, stream>>>(
      HallT, Wbig, xg, c, out + 3 * BKT, out + 3 * BKT + BH, bar);

  fe_kernel<<<128, 512, 0, stream>>>(HallT, Wfeb, b_fe, fe);
  z_kernel<<<2048, 256, 0, stream>>>(eps, fe, out);
}

// Round 3
// 1284.405 us; speedup vs baseline: 1.2626x; 1.2626x over previous
//
#include <hip/hip_runtime.h>
#include <math.h>

// ---------------------------------------------------------------------------
// RecurrentEncoder: LSTM (B=256, D=2048, H=2048, T=32) + emission head (K=64)
// Round 6: persistent loop, stall-bound fixes. Keep 8-wave 32x32 structure.
//  - xg preloaded ONCE into 16 VGPRs (tick-invariant; was re-fetched from LLC
//    every tick after the barrier's L2 invalidate).
//  - c lives in 16 VGPRs (tick-carried, block-private); c buffer deleted.
//  - A ring deepened 8->12 and B-fragments prefetched 1 step ahead into regs
//    (VGPR budget: 2 waves/SIMD allows 256; __launch_bounds__(512,2)).
//  - t=0 GEMM skipped (h0 = 0), HallT slot-0 memset dropped.
// ---------------------------------------------------------------------------

typedef short  short8  __attribute__((ext_vector_type(8)));   // 8 x bf16
typedef float  floatx4 __attribute__((ext_vector_type(4)));

#define BB 256
#define HH 2048
#define G4 8192
#define KK 64
#define TT 32

__device__ __forceinline__ unsigned short f2bf(float f) {
  union { float f; unsigned int u; } v; v.f = f;
  unsigned int u = v.u;
  u += 0x7fffu + ((u >> 16) & 1u);   // round-to-nearest-even
  return (unsigned short)(u >> 16);
}
__device__ __forceinline__ float sigmoidf_(float x) { return 1.0f / (1.0f + __expf(-x)); }
__device__ __forceinline__ float softplusf_(float x) {
  return (x > 20.0f) ? x : log1pf(__expf(x));
}
__device__ __forceinline__ short8 cvt8(const float* __restrict__ s) {
  float4 a = reinterpret_cast<const float4*>(s)[0];
  float4 b = reinterpret_cast<const float4*>(s)[1];
  short8 o;
  o[0] = f2bf(a.x); o[1] = f2bf(a.y); o[2] = f2bf(a.z); o[3] = f2bf(a.w);
  o[4] = f2bf(b.x); o[5] = f2bf(b.y); o[6] = f2bf(b.z); o[7] = f2bf(b.w);
  return o;
}

// ---------------------------------------------------------------------------
// Weight transform: fp32 row-major [q or gate-major][K] ->
// bf16 chunks [blk][phase 2][k8 128][col 32][8elem]  (exact LDS slab layout).
// PERM=1: q = u*4+g  ->  src row g*2048+u  (LSTM gate interleave).
// ---------------------------------------------------------------------------
template <int PERM>
__global__ void cvt_w_kernel(const float* __restrict__ in,
                             unsigned short* __restrict__ out, int total) {
  int tid = blockIdx.x * 256 + threadIdx.x;
  if (tid >= total) return;
  int col = tid & 31;
  int k4  = (tid >> 5) & 63;    // pair index: k8 = 2*k4
  int ph  = (tid >> 11) & 1;
  int blk = tid >> 12;
  int q = blk * 32 + col;
  int srcrow = PERM ? ((q & 3) * HH + (q >> 2)) : q;
  const float* src = in + (size_t)srcrow * HH + (ph * 128 + k4 * 2) * 8;
  short8 o0 = cvt8(src);
  short8 o1 = cvt8(src + 8);
  size_t ch = ((size_t)(blk * 2 + ph) * 128 + k4 * 2) * 32 + col;
  reinterpret_cast<short8*>(out)[ch]      = o0;
  reinterpret_cast<short8*>(out)[ch + 32] = o1;
}

// x fp32 [256][2048] -> x^T chunks [k8 256][row 256][8]
__global__ void cvt_x_kernel(const float* __restrict__ in,
                             unsigned short* __restrict__ out) {
  int tid = blockIdx.x * 256 + threadIdx.x;   // 65536
  int row = tid & 255, k8 = tid >> 8;
  short8 o = cvt8(in + (size_t)row * HH + k8 * 8);
  reinterpret_cast<short8*>(out)[tid] = o;    // chunk = k8*256 + row
}

// ---------------------------------------------------------------------------
// Core GEMM (used by xg / fe): 256 rows x 32 cols x K2048. W staged via LDS
// in two 64 KB phases; A ring-prefetched depth 4.
// ---------------------------------------------------------------------------
__device__ __forceinline__ void core_gemm(const short8* __restrict__ A8,
                                          const short8* __restrict__ Wg8,
                                          short8* L8, floatx4 acc[2][2]) {
  const int tid = threadIdx.x;
  const int lane = tid & 63, wave = tid >> 6;
  const int l15 = lane & 15, l4 = lane >> 4;
  const short8* Lr = L8 + l4 * 32 + l15;          // + kt*128 + ct*16
  const int abase = l4 * 256 + wave * 32 + l15;   // chunk = k8*256 + row (+rt*16)
  for (int ph = 0; ph < 2; ++ph) {
    __syncthreads();   // protect slab from previous phase's readers
#pragma unroll
    for (int j = 0; j < 8; ++j)
      L8[tid + j * 512] = Wg8[ph * 4096 + tid + j * 512];
    __syncthreads();
    short8 Ar[4][2];
#pragma unroll
    for (int i = 0; i < 4; ++i) {
      Ar[i][0] = A8[abase +      (ph * 128 + i * 4) * 256];
      Ar[i][1] = A8[abase + 16 + (ph * 128 + i * 4) * 256];
    }
#pragma unroll
    for (int kt = 0; kt < 32; ++kt) {
      short8 a0 = Ar[kt & 3][0], a1 = Ar[kt & 3][1];
      if (kt < 28) {
        Ar[kt & 3][0] = A8[abase +      (ph * 128 + (kt + 4) * 4) * 256];
        Ar[kt & 3][1] = A8[abase + 16 + (ph * 128 + (kt + 4) * 4) * 256];
      }
      short8 b0 = Lr[kt * 128];
      short8 b1 = Lr[kt * 128 + 16];
      acc[0][0] = __builtin_amdgcn_mfma_f32_16x16x32_bf16(a0, b0, acc[0][0], 0, 0, 0);
      acc[0][1] = __builtin_amdgcn_mfma_f32_16x16x32_bf16(a0, b1, acc[0][1], 0, 0, 0);
      acc[1][0] = __builtin_amdgcn_mfma_f32_16x16x32_bf16(a1, b0, acc[1][0], 0, 0, 0);
      acc[1][1] = __builtin_amdgcn_mfma_f32_16x16x32_bf16(a1, b1, acc[1][1], 0, 0, 0);
    }
  }
}

// ---------------------------------------------------------------------------
// Persistent LSTM loop. 256 blocks x 512 threads, plain launch. 128 KB W slab
// resident in LDS for all 32 ticks (1 block/CU => co-resident by capacity).
// xg and c live in registers for the whole kernel. Per tick (t>0):
// depth-12 A ring + 1-ahead B reg ring -> 256x32 GEMM -> gate epilogue
// (register c) -> h^T write -> device-scope grid barrier.
// ---------------------------------------------------------------------------
__global__ __launch_bounds__(512, 2) void lstm_loop_kernel(
    unsigned short* __restrict__ HallT, const unsigned short* __restrict__ Wt2,
    const float* __restrict__ xg, float* __restrict__ outh,
    float* __restrict__ outc, unsigned int* __restrict__ bar) {
  __shared__ __align__(16) unsigned short Wlds[65536];   // 128 KB
  const int tid = threadIdx.x;
  const int lane = tid & 63, wave = tid >> 6;
  const int l15 = lane & 15, l4 = lane >> 4;
  const int qb = blockIdx.x * 32, rw = wave * 32;
  const int gate = l15 & 3;
  const int base = lane & ~3;

  // xg is tick-invariant: load ONCE into registers (issue before LDS fill so
  // the latency hides under it).
  float xgr[2][2][4];
#pragma unroll
  for (int rt = 0; rt < 2; ++rt)
#pragma unroll
    for (int ct = 0; ct < 2; ++ct) {
      const int q = qb + ct * 16 + l15;
#pragma unroll
      for (int r = 0; r < 4; ++r) {
        const int row = rw + rt * 16 + l4 * 4 + r;
        xgr[rt][ct][r] = xg[(size_t)row * G4 + q];
      }
    }

  short8* L8 = reinterpret_cast<short8*>(Wlds);
  {
    const short8* Wg8 = reinterpret_cast<const short8*>(Wt2)
                        + (size_t)blockIdx.x * 8192;
#pragma unroll
    for (int j = 0; j < 16; ++j)
      L8[tid + j * 512] = Wg8[tid + j * 512];
  }
  __syncthreads();

  const short8* Lr = L8 + l4 * 32 + l15;          // + kt*128 + ct*16
  const int abase = l4 * 256 + wave * 32 + l15;   // chunk = k8*256 + row (+rt*16)

  // Cell state: tick-carried, block-private -> registers (gate==0 lanes hold
  // the live values; other lanes carry dead copies).
  float creg[2][2][4];
#pragma unroll
  for (int rt = 0; rt < 2; ++rt)
#pragma unroll
    for (int ct = 0; ct < 2; ++ct)
#pragma unroll
      for (int r = 0; r < 4; ++r) creg[rt][ct][r] = 0.0f;

#pragma unroll 1
  for (int t = 0; t < TT; ++t) {
    unsigned short* Hout = HallT + (size_t)(t + 1) * 524288;

    floatx4 acc[2][2];
    floatx4 z4 = {0.f, 0.f, 0.f, 0.f};
    acc[0][0] = z4; acc[0][1] = z4; acc[1][0] = z4; acc[1][1] = z4;

    if (t > 0) {   // t==0: h0 = 0 -> GEMM contributes nothing
      const short8* Ap = reinterpret_cast<const short8*>(HallT)
                         + (size_t)t * 65536 + abase;
      // Depth-12 A ring (96 VGPR) + 1-ahead B register ring.
      short8 Ar[12][2];
#pragma unroll
      for (int i = 0; i < 12; ++i) {
        Ar[i][0] = Ap[i * 1024];
        Ar[i][1] = Ap[i * 1024 + 16];
      }
      short8 Br[2][2];
      Br[0][0] = Lr[0];
      Br[0][1] = Lr[16];
#pragma unroll
      for (int kt = 0; kt < 64; ++kt) {
        short8 a0 = Ar[kt % 12][0], a1 = Ar[kt % 12][1];
        short8 b0 = Br[kt & 1][0],  b1 = Br[kt & 1][1];
        if (kt < 63) {
          Br[(kt + 1) & 1][0] = Lr[(kt + 1) * 128];
          Br[(kt + 1) & 1][1] = Lr[(kt + 1) * 128 + 16];
        }
        if (kt < 52) {
          Ar[kt % 12][0] = Ap[(kt + 12) * 1024];
          Ar[kt % 12][1] = Ap[(kt + 12) * 1024 + 16];
        }
        acc[0][0] = __builtin_amdgcn_mfma_f32_16x16x32_bf16(a0, b0, acc[0][0], 0, 0, 0);
        acc[0][1] = __builtin_amdgcn_mfma_f32_16x16x32_bf16(a0, b1, acc[0][1], 0, 0, 0);
        acc[1][0] = __builtin_amdgcn_mfma_f32_16x16x32_bf16(a1, b0, acc[1][0], 0, 0, 0);
        acc[1][1] = __builtin_amdgcn_mfma_f32_16x16x32_bf16(a1, b1, acc[1][1], 0, 0, 0);
      }
    }

    const int last = (t == TT - 1);
#pragma unroll
    for (int rt = 0; rt < 2; ++rt)
#pragma unroll
      for (int ct = 0; ct < 2; ++ct) {
        const floatx4 av = acc[rt][ct];
        const int q = qb + ct * 16 + l15;
        const int u = q >> 2;
#pragma unroll
        for (int r = 0; r < 4; ++r) {
          const int row = rw + rt * 16 + l4 * 4 + r;
          float g = av[r] + xgr[rt][ct][r];
          float act = (gate == 2) ? tanhf(g) : sigmoidf_(g);
          float iv = __shfl(act, base);
          float fv = __shfl(act, base + 1);
          float gv = __shfl(act, base + 2);
          float ov = __shfl(act, base + 3);
          if (gate == 0) {
            float cnew = fv * creg[rt][ct][r] + iv * gv;
            float hnew = ov * tanhf(cnew);
            creg[rt][ct][r] = cnew;
            Hout[(size_t)(blockIdx.x * 256 + row) * 8 + (u & 7)] = f2bf(hnew);
            if (last) {
              const size_t ci = (size_t)row * HH + u;
              outh[ci] = hnew; outc[ci] = cnew;
            }
          }
        }
      }

    if (t < TT - 1) {
      // ---- device-scope grid barrier (all 256 blocks resident, 1/CU) ----
      __syncthreads();   // drains vmcnt(0): all waves' h stores are in L2
      if (tid == 0) {
        __hip_atomic_fetch_add(bar, 1u, __ATOMIC_RELEASE,
                               __HIP_MEMORY_SCOPE_AGENT);
        const unsigned int target = (unsigned int)(t + 1) * 256u;
        while (__hip_atomic_load(bar, __ATOMIC_ACQUIRE,
                                 __HIP_MEMORY_SCOPE_AGENT) < target)
          __builtin_amdgcn_s_sleep(2);
      }
      __syncthreads();
    }
  }
}

// xg = x @ W_ih^T (q-permuted cols) + b_ih + b_hh
__global__ __launch_bounds__(512) void xg_kernel(
    const unsigned short* __restrict__ XT, const unsigned short* __restrict__ Wih,
    const float* __restrict__ b_ih, const float* __restrict__ b_hh,
    float* __restrict__ xg) {
  __shared__ __align__(16) unsigned short Wlds[32768];
  floatx4 acc[2][2];
  floatx4 z4 = {0.f, 0.f, 0.f, 0.f};
  acc[0][0] = z4; acc[0][1] = z4; acc[1][0] = z4; acc[1][1] = z4;
  core_gemm(reinterpret_cast<const short8*>(XT),
            reinterpret_cast<const short8*>(Wih) + (size_t)blockIdx.x * 8192,
            reinterpret_cast<short8*>(Wlds), acc);

  const int tid = threadIdx.x, lane = tid & 63, wave = tid >> 6;
  const int l15 = lane & 15, l4 = lane >> 4;
  const int qb = blockIdx.x * 32, rw = wave * 32;
#pragma unroll
  for (int rt = 0; rt < 2; ++rt)
#pragma unroll
    for (int ct = 0; ct < 2; ++ct) {
      const int q = qb + ct * 16 + l15;
      const float bias = b_ih[(q & 3) * HH + (q >> 2)] + b_hh[(q & 3) * HH + (q >> 2)];
#pragma unroll
      for (int r = 0; r < 4; ++r) {
        const int row = rw + rt * 16 + l4 * 4 + r;
        xg[(size_t)row * G4 + q] = acc[rt][ct][r] + bias;
      }
    }
}

// fe = h_t @ W_fe^T + b_fe for all t: block = (t, colgroup of 32)
__global__ __launch_bounds__(512) void fe_kernel(
    const unsigned short* __restrict__ HallT, const unsigned short* __restrict__ Wfe,
    const float* __restrict__ b_fe, float* __restrict__ fe) {
  const int t = blockIdx.x >> 2, cg_ = blockIdx.x & 3;
  __shared__ __align__(16) unsigned short Wlds[32768];
  floatx4 acc[2][2];
  floatx4 z4 = {0.f, 0.f, 0.f, 0.f};
  acc[0][0] = z4; acc[0][1] = z4; acc[1][0] = z4; acc[1][1] = z4;
  core_gemm(reinterpret_cast<const short8*>(HallT) + (size_t)(t + 1) * 65536,
            reinterpret_cast<const short8*>(Wfe) + (size_t)cg_ * 8192,
            reinterpret_cast<short8*>(Wlds), acc);

  const int tid = threadIdx.x, lane = tid & 63, wave = tid >> 6;
  const int l15 = lane & 15, l4 = lane >> 4;
  const int rw = wave * 32;
#pragma unroll
  for (int rt = 0; rt < 2; ++rt)
#pragma unroll
    for (int ct = 0; ct < 2; ++ct) {
      const int col = cg_ * 32 + ct * 16 + l15;
      const float bias = b_fe[col];
#pragma unroll
      for (int r = 0; r < 4; ++r) {
        const int row = rw + rt * 16 + l4 * 4 + r;
        fe[((size_t)t * 256 + row) * 128 + col] = acc[rt][ct][r] + bias;
      }
    }
}

// z = eps*softplus(fe[:,64:]-5) + fe[:,:64]; outputs laid out (B,K,T)
__global__ void z_kernel(const float* __restrict__ eps, const float* __restrict__ fe,
                         float* __restrict__ out) {
  const int tid = blockIdx.x * blockDim.x + threadIdx.x;  // 524288 = T*B*K
  const int tt = tid >> 14;
  const int b = (tid >> 6) & 255;
  const int k = tid & 63;
  const int frow = tt * 256 + b;
  const float mus = fe[frow * 128 + k];
  const float sig = softplusf_(fe[frow * 128 + 64 + k] - 5.0f);
  const float z = eps[tid] * sig + mus;
  const int o = (b * KK + k) * TT + tt;
  out[o] = z;
  out[524288 + o] = mus;
  out[2 * 524288 + o] = sig;
}

extern "C" void kernel_launch(void* const* d_in, const int* in_sizes, int n_in,
                              void* d_out, int out_size, void* d_ws, size_t ws_size,
                              hipStream_t stream) {
  const float* x    = (const float*)d_in[0];
  const float* eps  = (const float*)d_in[1];
  const float* W_ih = (const float*)d_in[2];
  const float* W_hh = (const float*)d_in[3];
  const float* b_ih = (const float*)d_in[4];
  const float* b_hh = (const float*)d_in[5];
  const float* W_fe = (const float*)d_in[6];
  const float* b_fe = (const float*)d_in[7];
  float* out = (float*)d_out;

  const size_t BH  = (size_t)BB * HH;       // 524288
  const size_t BKT = (size_t)BB * KK * TT;  // 524288

  char* p = (char*)d_ws;
  auto nxt = [&](size_t bytes) -> char* {
    char* r = p; p += (bytes + 255) & ~(size_t)255; return r;
  };
  unsigned short* Wbig  = (unsigned short*)nxt((size_t)G4 * HH * 2);       // 32 MB, W_ih then W_hh
  float*          xg    = (float*)nxt((size_t)BB * G4 * 4);                // 8 MB
  unsigned short* HallT = (unsigned short*)nxt((size_t)(TT + 1) * BH * 2); // 33 MB
  unsigned short* XT    = (unsigned short*)nxt(BH * 2);                    // 1 MB
  unsigned short* Wfeb  = (unsigned short*)nxt((size_t)128 * HH * 2);      // 0.5 MB
  float*          fe    = (float*)nxt((size_t)(TT * BB) * 128 * 4);        // 4 MB
  unsigned int*   bar   = (unsigned int*)nxt(256);                         // grid barrier

  hipMemsetAsync(bar, 0, 256, stream);

  cvt_x_kernel<<<256, 256, 0, stream>>>(x, XT);
  cvt_w_kernel<0><<<64, 256, 0, stream>>>(W_fe, Wfeb, 16384);
  cvt_w_kernel<1><<<4096, 256, 0, stream>>>(W_ih, Wbig, 1048576);
  xg_kernel<<<256, 512, 0, stream>>>(XT, Wbig, b_ih, b_hh, xg);
  cvt_w_kernel<1><<<4096, 256, 0, stream>>>(W_hh, Wbig, 1048576);

  lstm_loop_kernel<<<256, 512, 0, stream>>>(
      HallT, Wbig, xg, out + 3 * BKT, out + 3 * BKT + BH, bar);

  fe_kernel<<<128, 512, 0, stream>>>(HallT, Wfeb, b_fe, fe);
  z_kernel<<<2048, 256, 0, stream>>>(eps, fe, out);
}

// Round 4
// 1199.057 us; speedup vs baseline: 1.3525x; 1.0712x over previous
//
#include <hip/hip_runtime.h>
#include <math.h>

// ---------------------------------------------------------------------------
// RecurrentEncoder: LSTM (B=256, D=2048, H=2048, T=32) + emission head (K=64)
// Round 7: keep R6 structure (persistent loop, W LDS-resident, xg/c in regs);
// fix the collapsed A-prefetch ring. R6 reported VGPR=124 => compiler sank
// the depth-12 ring loads to their uses (effective depth ~4-6, ~200cy cover
// vs ~400-900cy post-barrier LLC latency). Now: depth-16 ring + per-kt
// __builtin_amdgcn_sched_barrier(0) fence between the issue group (A global
// loads + B ds_reads) and the 4 MFMAs, so the scheduler cannot collapse the
// pipeline. Expect VGPR ~200 (the diagnostic that the pin held).
// ---------------------------------------------------------------------------

typedef short  short8  __attribute__((ext_vector_type(8)));   // 8 x bf16
typedef float  floatx4 __attribute__((ext_vector_type(4)));

#define BB 256
#define HH 2048
#define G4 8192
#define KK 64
#define TT 32

__device__ __forceinline__ unsigned short f2bf(float f) {
  union { float f; unsigned int u; } v; v.f = f;
  unsigned int u = v.u;
  u += 0x7fffu + ((u >> 16) & 1u);   // round-to-nearest-even
  return (unsigned short)(u >> 16);
}
__device__ __forceinline__ float sigmoidf_(float x) { return 1.0f / (1.0f + __expf(-x)); }
__device__ __forceinline__ float softplusf_(float x) {
  return (x > 20.0f) ? x : log1pf(__expf(x));
}
__device__ __forceinline__ short8 cvt8(const float* __restrict__ s) {
  float4 a = reinterpret_cast<const float4*>(s)[0];
  float4 b = reinterpret_cast<const float4*>(s)[1];
  short8 o;
  o[0] = f2bf(a.x); o[1] = f2bf(a.y); o[2] = f2bf(a.z); o[3] = f2bf(a.w);
  o[4] = f2bf(b.x); o[5] = f2bf(b.y); o[6] = f2bf(b.z); o[7] = f2bf(b.w);
  return o;
}

// ---------------------------------------------------------------------------
// Weight transform: fp32 row-major [q or gate-major][K] ->
// bf16 chunks [blk][phase 2][k8 128][col 32][8elem]  (exact LDS slab layout).
// PERM=1: q = u*4+g  ->  src row g*2048+u  (LSTM gate interleave).
// ---------------------------------------------------------------------------
template <int PERM>
__global__ void cvt_w_kernel(const float* __restrict__ in,
                             unsigned short* __restrict__ out, int total) {
  int tid = blockIdx.x * 256 + threadIdx.x;
  if (tid >= total) return;
  int col = tid & 31;
  int k4  = (tid >> 5) & 63;    // pair index: k8 = 2*k4
  int ph  = (tid >> 11) & 1;
  int blk = tid >> 12;
  int q = blk * 32 + col;
  int srcrow = PERM ? ((q & 3) * HH + (q >> 2)) : q;
  const float* src = in + (size_t)srcrow * HH + (ph * 128 + k4 * 2) * 8;
  short8 o0 = cvt8(src);
  short8 o1 = cvt8(src + 8);
  size_t ch = ((size_t)(blk * 2 + ph) * 128 + k4 * 2) * 32 + col;
  reinterpret_cast<short8*>(out)[ch]      = o0;
  reinterpret_cast<short8*>(out)[ch + 32] = o1;
}

// x fp32 [256][2048] -> x^T chunks [k8 256][row 256][8]
__global__ void cvt_x_kernel(const float* __restrict__ in,
                             unsigned short* __restrict__ out) {
  int tid = blockIdx.x * 256 + threadIdx.x;   // 65536
  int row = tid & 255, k8 = tid >> 8;
  short8 o = cvt8(in + (size_t)row * HH + k8 * 8);
  reinterpret_cast<short8*>(out)[tid] = o;    // chunk = k8*256 + row
}

// ---------------------------------------------------------------------------
// Core GEMM (used by xg / fe): 256 rows x 32 cols x K2048. W staged via LDS
// in two 64 KB phases; A ring-prefetched depth 4.
// ---------------------------------------------------------------------------
__device__ __forceinline__ void core_gemm(const short8* __restrict__ A8,
                                          const short8* __restrict__ Wg8,
                                          short8* L8, floatx4 acc[2][2]) {
  const int tid = threadIdx.x;
  const int lane = tid & 63, wave = tid >> 6;
  const int l15 = lane & 15, l4 = lane >> 4;
  const short8* Lr = L8 + l4 * 32 + l15;          // + kt*128 + ct*16
  const int abase = l4 * 256 + wave * 32 + l15;   // chunk = k8*256 + row (+rt*16)
  for (int ph = 0; ph < 2; ++ph) {
    __syncthreads();   // protect slab from previous phase's readers
#pragma unroll
    for (int j = 0; j < 8; ++j)
      L8[tid + j * 512] = Wg8[ph * 4096 + tid + j * 512];
    __syncthreads();
    short8 Ar[4][2];
#pragma unroll
    for (int i = 0; i < 4; ++i) {
      Ar[i][0] = A8[abase +      (ph * 128 + i * 4) * 256];
      Ar[i][1] = A8[abase + 16 + (ph * 128 + i * 4) * 256];
    }
#pragma unroll
    for (int kt = 0; kt < 32; ++kt) {
      short8 a0 = Ar[kt & 3][0], a1 = Ar[kt & 3][1];
      if (kt < 28) {
        Ar[kt & 3][0] = A8[abase +      (ph * 128 + (kt + 4) * 4) * 256];
        Ar[kt & 3][1] = A8[abase + 16 + (ph * 128 + (kt + 4) * 4) * 256];
      }
      short8 b0 = Lr[kt * 128];
      short8 b1 = Lr[kt * 128 + 16];
      acc[0][0] = __builtin_amdgcn_mfma_f32_16x16x32_bf16(a0, b0, acc[0][0], 0, 0, 0);
      acc[0][1] = __builtin_amdgcn_mfma_f32_16x16x32_bf16(a0, b1, acc[0][1], 0, 0, 0);
      acc[1][0] = __builtin_amdgcn_mfma_f32_16x16x32_bf16(a1, b0, acc[1][0], 0, 0, 0);
      acc[1][1] = __builtin_amdgcn_mfma_f32_16x16x32_bf16(a1, b1, acc[1][1], 0, 0, 0);
    }
  }
}

// ---------------------------------------------------------------------------
// Persistent LSTM loop. 256 blocks x 512 threads, plain launch. 128 KB W slab
// resident in LDS for all 32 ticks (1 block/CU => co-resident by capacity).
// xg and c live in registers for the whole kernel. Per tick (t>0):
// depth-16 A ring (sched_barrier-pinned) -> 256x32 GEMM -> gate epilogue
// (register c) -> h^T write -> device-scope grid barrier.
// ---------------------------------------------------------------------------
__global__ __launch_bounds__(512, 2) void lstm_loop_kernel(
    unsigned short* __restrict__ HallT, const unsigned short* __restrict__ Wt2,
    const float* __restrict__ xg, float* __restrict__ outh,
    float* __restrict__ outc, unsigned int* __restrict__ bar) {
  __shared__ __align__(16) unsigned short Wlds[65536];   // 128 KB
  const int tid = threadIdx.x;
  const int lane = tid & 63, wave = tid >> 6;
  const int l15 = lane & 15, l4 = lane >> 4;
  const int qb = blockIdx.x * 32, rw = wave * 32;
  const int gate = l15 & 3;
  const int base = lane & ~3;

  // xg is tick-invariant: load ONCE into registers (issue before LDS fill so
  // the latency hides under it).
  float xgr[2][2][4];
#pragma unroll
  for (int rt = 0; rt < 2; ++rt)
#pragma unroll
    for (int ct = 0; ct < 2; ++ct) {
      const int q = qb + ct * 16 + l15;
#pragma unroll
      for (int r = 0; r < 4; ++r) {
        const int row = rw + rt * 16 + l4 * 4 + r;
        xgr[rt][ct][r] = xg[(size_t)row * G4 + q];
      }
    }

  short8* L8 = reinterpret_cast<short8*>(Wlds);
  {
    const short8* Wg8 = reinterpret_cast<const short8*>(Wt2)
                        + (size_t)blockIdx.x * 8192;
#pragma unroll
    for (int j = 0; j < 16; ++j)
      L8[tid + j * 512] = Wg8[tid + j * 512];
  }
  __syncthreads();

  const short8* Lr = L8 + l4 * 32 + l15;          // + kt*128 + ct*16
  const int abase = l4 * 256 + wave * 32 + l15;   // chunk = k8*256 + row (+rt*16)

  // Cell state: tick-carried, block-private -> registers (gate==0 lanes hold
  // the live values; other lanes carry dead copies).
  float creg[2][2][4];
#pragma unroll
  for (int rt = 0; rt < 2; ++rt)
#pragma unroll
    for (int ct = 0; ct < 2; ++ct)
#pragma unroll
      for (int r = 0; r < 4; ++r) creg[rt][ct][r] = 0.0f;

#pragma unroll 1
  for (int t = 0; t < TT; ++t) {
    unsigned short* Hout = HallT + (size_t)(t + 1) * 524288;

    floatx4 acc[2][2];
    floatx4 z4 = {0.f, 0.f, 0.f, 0.f};
    acc[0][0] = z4; acc[0][1] = z4; acc[1][0] = z4; acc[1][1] = z4;

    if (t > 0) {   // t==0: h0 = 0 -> GEMM contributes nothing
      const short8* Ap = reinterpret_cast<const short8*>(HallT)
                         + (size_t)t * 65536 + abase;
      // Depth-16 A ring (128 VGPR) + 1-ahead B register ring. Each kt:
      // {issue next A pair + next B pair} SCHED_BARRIER {4 MFMA}. The fence
      // prevents the scheduler from sinking the ring loads to their uses
      // (which is what collapsed the R6 pipeline to ~6 deep).
      short8 Ar[16][2];
#pragma unroll
      for (int i = 0; i < 16; ++i) {
        Ar[i][0] = Ap[i * 1024];
        Ar[i][1] = Ap[i * 1024 + 16];
      }
      short8 Br[2][2];
      Br[0][0] = Lr[0];
      Br[0][1] = Lr[16];
#pragma unroll
      for (int kt = 0; kt < 64; ++kt) {
        short8 a0 = Ar[kt & 15][0], a1 = Ar[kt & 15][1];
        short8 b0 = Br[kt & 1][0],  b1 = Br[kt & 1][1];
        if (kt < 63) {
          Br[(kt + 1) & 1][0] = Lr[(kt + 1) * 128];
          Br[(kt + 1) & 1][1] = Lr[(kt + 1) * 128 + 16];
        }
        if (kt < 48) {
          Ar[kt & 15][0] = Ap[(kt + 16) * 1024];
          Ar[kt & 15][1] = Ap[(kt + 16) * 1024 + 16];
        }
        __builtin_amdgcn_sched_barrier(0);   // pin issue group above MFMAs
        acc[0][0] = __builtin_amdgcn_mfma_f32_16x16x32_bf16(a0, b0, acc[0][0], 0, 0, 0);
        acc[0][1] = __builtin_amdgcn_mfma_f32_16x16x32_bf16(a0, b1, acc[0][1], 0, 0, 0);
        acc[1][0] = __builtin_amdgcn_mfma_f32_16x16x32_bf16(a1, b0, acc[1][0], 0, 0, 0);
        acc[1][1] = __builtin_amdgcn_mfma_f32_16x16x32_bf16(a1, b1, acc[1][1], 0, 0, 0);
      }
    }

    const int last = (t == TT - 1);
#pragma unroll
    for (int rt = 0; rt < 2; ++rt)
#pragma unroll
      for (int ct = 0; ct < 2; ++ct) {
        const floatx4 av = acc[rt][ct];
        const int q = qb + ct * 16 + l15;
        const int u = q >> 2;
#pragma unroll
        for (int r = 0; r < 4; ++r) {
          const int row = rw + rt * 16 + l4 * 4 + r;
          float g = av[r] + xgr[rt][ct][r];
          float act = (gate == 2) ? tanhf(g) : sigmoidf_(g);
          float iv = __shfl(act, base);
          float fv = __shfl(act, base + 1);
          float gv = __shfl(act, base + 2);
          float ov = __shfl(act, base + 3);
          if (gate == 0) {
            float cnew = fv * creg[rt][ct][r] + iv * gv;
            float hnew = ov * tanhf(cnew);
            creg[rt][ct][r] = cnew;
            Hout[(size_t)(blockIdx.x * 256 + row) * 8 + (u & 7)] = f2bf(hnew);
            if (last) {
              const size_t ci = (size_t)row * HH + u;
              outh[ci] = hnew; outc[ci] = cnew;
            }
          }
        }
      }

    if (t < TT - 1) {
      // ---- device-scope grid barrier (all 256 blocks resident, 1/CU) ----
      __syncthreads();   // drains vmcnt(0): all waves' h stores are in L2
      if (tid == 0) {
        __hip_atomic_fetch_add(bar, 1u, __ATOMIC_RELEASE,
                               __HIP_MEMORY_SCOPE_AGENT);
        const unsigned int target = (unsigned int)(t + 1) * 256u;
        while (__hip_atomic_load(bar, __ATOMIC_ACQUIRE,
                                 __HIP_MEMORY_SCOPE_AGENT) < target)
          __builtin_amdgcn_s_sleep(2);
      }
      __syncthreads();
    }
  }
}

// xg = x @ W_ih^T (q-permuted cols) + b_ih + b_hh
__global__ __launch_bounds__(512) void xg_kernel(
    const unsigned short* __restrict__ XT, const unsigned short* __restrict__ Wih,
    const float* __restrict__ b_ih, const float* __restrict__ b_hh,
    float* __restrict__ xg) {
  __shared__ __align__(16) unsigned short Wlds[32768];
  floatx4 acc[2][2];
  floatx4 z4 = {0.f, 0.f, 0.f, 0.f};
  acc[0][0] = z4; acc[0][1] = z4; acc[1][0] = z4; acc[1][1] = z4;
  core_gemm(reinterpret_cast<const short8*>(XT),
            reinterpret_cast<const short8*>(Wih) + (size_t)blockIdx.x * 8192,
            reinterpret_cast<short8*>(Wlds), acc);

  const int tid = threadIdx.x, lane = tid & 63, wave = tid >> 6;
  const int l15 = lane & 15, l4 = lane >> 4;
  const int qb = blockIdx.x * 32, rw = wave * 32;
#pragma unroll
  for (int rt = 0; rt < 2; ++rt)
#pragma unroll
    for (int ct = 0; ct < 2; ++ct) {
      const int q = qb + ct * 16 + l15;
      const float bias = b_ih[(q & 3) * HH + (q >> 2)] + b_hh[(q & 3) * HH + (q >> 2)];
#pragma unroll
      for (int r = 0; r < 4; ++r) {
        const int row = rw + rt * 16 + l4 * 4 + r;
        xg[(size_t)row * G4 + q] = acc[rt][ct][r] + bias;
      }
    }
}

// fe = h_t @ W_fe^T + b_fe for all t: block = (t, colgroup of 32)
__global__ __launch_bounds__(512) void fe_kernel(
    const unsigned short* __restrict__ HallT, const unsigned short* __restrict__ Wfe,
    const float* __restrict__ b_fe, float* __restrict__ fe) {
  const int t = blockIdx.x >> 2, cg_ = blockIdx.x & 3;
  __shared__ __align__(16) unsigned short Wlds[32768];
  floatx4 acc[2][2];
  floatx4 z4 = {0.f, 0.f, 0.f, 0.f};
  acc[0][0] = z4; acc[0][1] = z4; acc[1][0] = z4; acc[1][1] = z4;
  core_gemm(reinterpret_cast<const short8*>(HallT) + (size_t)(t + 1) * 65536,
            reinterpret_cast<const short8*>(Wfe) + (size_t)cg_ * 8192,
            reinterpret_cast<short8*>(Wlds), acc);

  const int tid = threadIdx.x, lane = tid & 63, wave = tid >> 6;
  const int l15 = lane & 15, l4 = lane >> 4;
  const int rw = wave * 32;
#pragma unroll
  for (int rt = 0; rt < 2; ++rt)
#pragma unroll
    for (int ct = 0; ct < 2; ++ct) {
      const int col = cg_ * 32 + ct * 16 + l15;
      const float bias = b_fe[col];
#pragma unroll
      for (int r = 0; r < 4; ++r) {
        const int row = rw + rt * 16 + l4 * 4 + r;
        fe[((size_t)t * 256 + row) * 128 + col] = acc[rt][ct][r] + bias;
      }
    }
}

// z = eps*softplus(fe[:,64:]-5) + fe[:,:64]; outputs laid out (B,K,T)
__global__ void z_kernel(const float* __restrict__ eps, const float* __restrict__ fe,
                         float* __restrict__ out) {
  const int tid = blockIdx.x * blockDim.x + threadIdx.x;  // 524288 = T*B*K
  const int tt = tid >> 14;
  const int b = (tid >> 6) & 255;
  const int k = tid & 63;
  const int frow = tt * 256 + b;
  const float mus = fe[frow * 128 + k];
  const float sig = softplusf_(fe[frow * 128 + 64 + k] - 5.0f);
  const float z = eps[tid] * sig + mus;
  const int o = (b * KK + k) * TT + tt;
  out[o] = z;
  out[524288 + o] = mus;
  out[2 * 524288 + o] = sig;
}

extern "C" void kernel_launch(void* const* d_in, const int* in_sizes, int n_in,
                              void* d_out, int out_size, void* d_ws, size_t ws_size,
                              hipStream_t stream) {
  const float* x    = (const float*)d_in[0];
  const float* eps  = (const float*)d_in[1];
  const float* W_ih = (const float*)d_in[2];
  const float* W_hh = (const float*)d_in[3];
  const float* b_ih = (const float*)d_in[4];
  const float* b_hh = (const float*)d_in[5];
  const float* W_fe = (const float*)d_in[6];
  const float* b_fe = (const float*)d_in[7];
  float* out = (float*)d_out;

  const size_t BH  = (size_t)BB * HH;       // 524288
  const size_t BKT = (size_t)BB * KK * TT;  // 524288

  char* p = (char*)d_ws;
  auto nxt = [&](size_t bytes) -> char* {
    char* r = p; p += (bytes + 255) & ~(size_t)255; return r;
  };
  unsigned short* Wbig  = (unsigned short*)nxt((size_t)G4 * HH * 2);       // 32 MB, W_ih then W_hh
  float*          xg    = (float*)nxt((size_t)BB * G4 * 4);                // 8 MB
  unsigned short* HallT = (unsigned short*)nxt((size_t)(TT + 1) * BH * 2); // 33 MB
  unsigned short* XT    = (unsigned short*)nxt(BH * 2);                    // 1 MB
  unsigned short* Wfeb  = (unsigned short*)nxt((size_t)128 * HH * 2);      // 0.5 MB
  float*          fe    = (float*)nxt((size_t)(TT * BB) * 128 * 4);        // 4 MB
  unsigned int*   bar   = (unsigned int*)nxt(256);                         // grid barrier

  hipMemsetAsync(bar, 0, 256, stream);

  cvt_x_kernel<<<256, 256, 0, stream>>>(x, XT);
  cvt_w_kernel<0><<<64, 256, 0, stream>>>(W_fe, Wfeb, 16384);
  cvt_w_kernel<1><<<4096, 256, 0, stream>>>(W_ih, Wbig, 1048576);
  xg_kernel<<<256, 512, 0, stream>>>(XT, Wbig, b_ih, b_hh, xg);
  cvt_w_kernel<1><<<4096, 256, 0, stream>>>(W_hh, Wbig, 1048576);

  lstm_loop_kernel<<<256, 512, 0, stream>>>(
      HallT, Wbig, xg, out + 3 * BKT, out + 3 * BKT + BH, bar);

  fe_kernel<<<128, 512, 0, stream>>>(HallT, Wfeb, b_fe, fe);
  z_kernel<<<2048, 256, 0, stream>>>(eps, fe, out);
}

// Round 5
// 1044.936 us; speedup vs baseline: 1.5519x; 1.1475x over previous
//
#include <hip/hip_runtime.h>
#include <math.h>

// ---------------------------------------------------------------------------
// RecurrentEncoder: LSTM (B=256, D=2048, H=2048, T=32) + emission head (K=64)
// Round 8: TLP instead of ILP. Persistent loop keeps W (128 KB) LDS-resident,
// xg/c in registers; the block is now 1024 threads = 16 waves = 4 waves/SIMD
// (was 8 waves = 2/SIMD). Each wave owns a 16x32 tile: 1 A-load + 2 MFMA per
// kt, depth-8 ring (32 VGPR, no pressure -> compiler keeps it). Post-barrier
// LLC latency (~900cy) is covered by 4-way wave interleave per SIMD, which
// three rounds of source-level pipeline pinning failed to do.
// ---------------------------------------------------------------------------

typedef short  short8  __attribute__((ext_vector_type(8)));   // 8 x bf16
typedef float  floatx4 __attribute__((ext_vector_type(4)));

#define BB 256
#define HH 2048
#define G4 8192
#define KK 64
#define TT 32

__device__ __forceinline__ unsigned short f2bf(float f) {
  union { float f; unsigned int u; } v; v.f = f;
  unsigned int u = v.u;
  u += 0x7fffu + ((u >> 16) & 1u);   // round-to-nearest-even
  return (unsigned short)(u >> 16);
}
__device__ __forceinline__ float sigmoidf_(float x) { return 1.0f / (1.0f + __expf(-x)); }
__device__ __forceinline__ float softplusf_(float x) {
  return (x > 20.0f) ? x : log1pf(__expf(x));
}
__device__ __forceinline__ short8 cvt8(const float* __restrict__ s) {
  float4 a = reinterpret_cast<const float4*>(s)[0];
  float4 b = reinterpret_cast<const float4*>(s)[1];
  short8 o;
  o[0] = f2bf(a.x); o[1] = f2bf(a.y); o[2] = f2bf(a.z); o[3] = f2bf(a.w);
  o[4] = f2bf(b.x); o[5] = f2bf(b.y); o[6] = f2bf(b.z); o[7] = f2bf(b.w);
  return o;
}

// ---------------------------------------------------------------------------
// Weight transform: fp32 row-major [q or gate-major][K] ->
// bf16 chunks [blk][phase 2][k8 128][col 32][8elem]  (exact LDS slab layout).
// PERM=1: q = u*4+g  ->  src row g*2048+u  (LSTM gate interleave).
// ---------------------------------------------------------------------------
template <int PERM>
__global__ void cvt_w_kernel(const float* __restrict__ in,
                             unsigned short* __restrict__ out, int total) {
  int tid = blockIdx.x * 256 + threadIdx.x;
  if (tid >= total) return;
  int col = tid & 31;
  int k4  = (tid >> 5) & 63;    // pair index: k8 = 2*k4
  int ph  = (tid >> 11) & 1;
  int blk = tid >> 12;
  int q = blk * 32 + col;
  int srcrow = PERM ? ((q & 3) * HH + (q >> 2)) : q;
  const float* src = in + (size_t)srcrow * HH + (ph * 128 + k4 * 2) * 8;
  short8 o0 = cvt8(src);
  short8 o1 = cvt8(src + 8);
  size_t ch = ((size_t)(blk * 2 + ph) * 128 + k4 * 2) * 32 + col;
  reinterpret_cast<short8*>(out)[ch]      = o0;
  reinterpret_cast<short8*>(out)[ch + 32] = o1;
}

// x fp32 [256][2048] -> x^T chunks [k8 256][row 256][8]
__global__ void cvt_x_kernel(const float* __restrict__ in,
                             unsigned short* __restrict__ out) {
  int tid = blockIdx.x * 256 + threadIdx.x;   // 65536
  int row = tid & 255, k8 = tid >> 8;
  short8 o = cvt8(in + (size_t)row * HH + k8 * 8);
  reinterpret_cast<short8*>(out)[tid] = o;    // chunk = k8*256 + row
}

// ---------------------------------------------------------------------------
// Core GEMM (used by xg / fe): 256 rows x 32 cols x K2048. W staged via LDS
// in two 64 KB phases; A ring-prefetched depth 4. (512-thread, 8-wave form.)
// ---------------------------------------------------------------------------
__device__ __forceinline__ void core_gemm(const short8* __restrict__ A8,
                                          const short8* __restrict__ Wg8,
                                          short8* L8, floatx4 acc[2][2]) {
  const int tid = threadIdx.x;
  const int lane = tid & 63, wave = tid >> 6;
  const int l15 = lane & 15, l4 = lane >> 4;
  const short8* Lr = L8 + l4 * 32 + l15;          // + kt*128 + ct*16
  const int abase = l4 * 256 + wave * 32 + l15;   // chunk = k8*256 + row (+rt*16)
  for (int ph = 0; ph < 2; ++ph) {
    __syncthreads();   // protect slab from previous phase's readers
#pragma unroll
    for (int j = 0; j < 8; ++j)
      L8[tid + j * 512] = Wg8[ph * 4096 + tid + j * 512];
    __syncthreads();
    short8 Ar[4][2];
#pragma unroll
    for (int i = 0; i < 4; ++i) {
      Ar[i][0] = A8[abase +      (ph * 128 + i * 4) * 256];
      Ar[i][1] = A8[abase + 16 + (ph * 128 + i * 4) * 256];
    }
#pragma unroll
    for (int kt = 0; kt < 32; ++kt) {
      short8 a0 = Ar[kt & 3][0], a1 = Ar[kt & 3][1];
      if (kt < 28) {
        Ar[kt & 3][0] = A8[abase +      (ph * 128 + (kt + 4) * 4) * 256];
        Ar[kt & 3][1] = A8[abase + 16 + (ph * 128 + (kt + 4) * 4) * 256];
      }
      short8 b0 = Lr[kt * 128];
      short8 b1 = Lr[kt * 128 + 16];
      acc[0][0] = __builtin_amdgcn_mfma_f32_16x16x32_bf16(a0, b0, acc[0][0], 0, 0, 0);
      acc[0][1] = __builtin_amdgcn_mfma_f32_16x16x32_bf16(a0, b1, acc[0][1], 0, 0, 0);
      acc[1][0] = __builtin_amdgcn_mfma_f32_16x16x32_bf16(a1, b0, acc[1][0], 0, 0, 0);
      acc[1][1] = __builtin_amdgcn_mfma_f32_16x16x32_bf16(a1, b1, acc[1][1], 0, 0, 0);
    }
  }
}

// ---------------------------------------------------------------------------
// Persistent LSTM loop. 256 blocks x 1024 threads (16 waves = 4/SIMD), plain
// launch. 128 KB W slab resident in LDS for all 32 ticks (1 block/CU =>
// co-resident by capacity). xg and c live in registers. Per tick (t>0):
// per-wave 16x32 tile, depth-8 A ring, 2 MFMA/kt -> gate epilogue (register
// c) -> h^T write -> device-scope grid barrier.
// ---------------------------------------------------------------------------
__global__ __launch_bounds__(1024) void lstm_loop_kernel(
    unsigned short* __restrict__ HallT, const unsigned short* __restrict__ Wt2,
    const float* __restrict__ xg, float* __restrict__ outh,
    float* __restrict__ outc, unsigned int* __restrict__ bar) {
  __shared__ __align__(16) unsigned short Wlds[65536];   // 128 KB
  const int tid = threadIdx.x;
  const int lane = tid & 63, wave = tid >> 6;   // wave 0..15
  const int l15 = lane & 15, l4 = lane >> 4;
  const int qb = blockIdx.x * 32, rw = wave * 16;
  const int gate = l15 & 3;
  const int base = lane & ~3;

  // xg is tick-invariant: load ONCE into registers (issue before LDS fill so
  // the latency hides under it).
  float xgr[2][4];
#pragma unroll
  for (int ct = 0; ct < 2; ++ct) {
    const int q = qb + ct * 16 + l15;
#pragma unroll
    for (int r = 0; r < 4; ++r) {
      const int row = rw + l4 * 4 + r;
      xgr[ct][r] = xg[(size_t)row * G4 + q];
    }
  }

  short8* L8 = reinterpret_cast<short8*>(Wlds);
  {
    const short8* Wg8 = reinterpret_cast<const short8*>(Wt2)
                        + (size_t)blockIdx.x * 8192;
#pragma unroll
    for (int j = 0; j < 8; ++j)
      L8[tid + j * 1024] = Wg8[tid + j * 1024];
  }
  __syncthreads();

  const short8* Lr = L8 + l4 * 32 + l15;          // + kt*128 + ct*16
  const int abase = l4 * 256 + wave * 16 + l15;   // chunk = k8*256 + row

  // Cell state: tick-carried, block-private -> registers (gate==0 lanes hold
  // the live values; other lanes carry dead copies).
  float creg[2][4];
#pragma unroll
  for (int ct = 0; ct < 2; ++ct)
#pragma unroll
    for (int r = 0; r < 4; ++r) creg[ct][r] = 0.0f;

#pragma unroll 1
  for (int t = 0; t < TT; ++t) {
    unsigned short* Hout = HallT + (size_t)(t + 1) * 524288;

    floatx4 acc[2];
    floatx4 z4 = {0.f, 0.f, 0.f, 0.f};
    acc[0] = z4; acc[1] = z4;

    if (t > 0) {   // t==0: h0 = 0 -> GEMM contributes nothing
      const short8* Ap = reinterpret_cast<const short8*>(HallT)
                         + (size_t)t * 65536 + abase;
      // Depth-8 A ring (32 VGPR, ample headroom under the 128 cap -> the
      // compiler has no pressure to collapse it). TLP (4 waves/SIMD) covers
      // whatever the ring doesn't.
      short8 Ar[8];
#pragma unroll
      for (int i = 0; i < 8; ++i) Ar[i] = Ap[i * 1024];
#pragma unroll
      for (int kt = 0; kt < 64; ++kt) {
        short8 a0 = Ar[kt & 7];
        if (kt < 56) Ar[kt & 7] = Ap[(kt + 8) * 1024];
        short8 b0 = Lr[kt * 128];
        short8 b1 = Lr[kt * 128 + 16];
        acc[0] = __builtin_amdgcn_mfma_f32_16x16x32_bf16(a0, b0, acc[0], 0, 0, 0);
        acc[1] = __builtin_amdgcn_mfma_f32_16x16x32_bf16(a0, b1, acc[1], 0, 0, 0);
      }
    }

    const int last = (t == TT - 1);
#pragma unroll
    for (int ct = 0; ct < 2; ++ct) {
      const floatx4 av = acc[ct];
      const int q = qb + ct * 16 + l15;
      const int u = q >> 2;
#pragma unroll
      for (int r = 0; r < 4; ++r) {
        const int row = rw + l4 * 4 + r;
        float g = av[r] + xgr[ct][r];
        float act = (gate == 2) ? tanhf(g) : sigmoidf_(g);
        float iv = __shfl(act, base);
        float fv = __shfl(act, base + 1);
        float gv = __shfl(act, base + 2);
        float ov = __shfl(act, base + 3);
        if (gate == 0) {
          float cnew = fv * creg[ct][r] + iv * gv;
          float hnew = ov * tanhf(cnew);
          creg[ct][r] = cnew;
          Hout[(size_t)(blockIdx.x * 256 + row) * 8 + (u & 7)] = f2bf(hnew);
          if (last) {
            const size_t ci = (size_t)row * HH + u;
            outh[ci] = hnew; outc[ci] = cnew;
          }
        }
      }
    }

    if (t < TT - 1) {
      // ---- device-scope grid barrier (all 256 blocks resident, 1/CU) ----
      __syncthreads();   // drains vmcnt(0): all waves' h stores are in L2
      if (tid == 0) {
        __hip_atomic_fetch_add(bar, 1u, __ATOMIC_RELEASE,
                               __HIP_MEMORY_SCOPE_AGENT);
        const unsigned int target = (unsigned int)(t + 1) * 256u;
        while (__hip_atomic_load(bar, __ATOMIC_ACQUIRE,
                                 __HIP_MEMORY_SCOPE_AGENT) < target)
          __builtin_amdgcn_s_sleep(2);
      }
      __syncthreads();
    }
  }
}

// xg = x @ W_ih^T (q-permuted cols) + b_ih + b_hh
__global__ __launch_bounds__(512) void xg_kernel(
    const unsigned short* __restrict__ XT, const unsigned short* __restrict__ Wih,
    const float* __restrict__ b_ih, const float* __restrict__ b_hh,
    float* __restrict__ xg) {
  __shared__ __align__(16) unsigned short Wlds[32768];
  floatx4 acc[2][2];
  floatx4 z4 = {0.f, 0.f, 0.f, 0.f};
  acc[0][0] = z4; acc[0][1] = z4; acc[1][0] = z4; acc[1][1] = z4;
  core_gemm(reinterpret_cast<const short8*>(XT),
            reinterpret_cast<const short8*>(Wih) + (size_t)blockIdx.x * 8192,
            reinterpret_cast<short8*>(Wlds), acc);

  const int tid = threadIdx.x, lane = tid & 63, wave = tid >> 6;
  const int l15 = lane & 15, l4 = lane >> 4;
  const int qb = blockIdx.x * 32, rw = wave * 32;
#pragma unroll
  for (int rt = 0; rt < 2; ++rt)
#pragma unroll
    for (int ct = 0; ct < 2; ++ct) {
      const int q = qb + ct * 16 + l15;
      const float bias = b_ih[(q & 3) * HH + (q >> 2)] + b_hh[(q & 3) * HH + (q >> 2)];
#pragma unroll
      for (int r = 0; r < 4; ++r) {
        const int row = rw + rt * 16 + l4 * 4 + r;
        xg[(size_t)row * G4 + q] = acc[rt][ct][r] + bias;
      }
    }
}

// fe = h_t @ W_fe^T + b_fe for all t: block = (t, colgroup of 32)
__global__ __launch_bounds__(512) void fe_kernel(
    const unsigned short* __restrict__ HallT, const unsigned short* __restrict__ Wfe,
    const float* __restrict__ b_fe, float* __restrict__ fe) {
  const int t = blockIdx.x >> 2, cg_ = blockIdx.x & 3;
  __shared__ __align__(16) unsigned short Wlds[32768];
  floatx4 acc[2][2];
  floatx4 z4 = {0.f, 0.f, 0.f, 0.f};
  acc[0][0] = z4; acc[0][1] = z4; acc[1][0] = z4; acc[1][1] = z4;
  core_gemm(reinterpret_cast<const short8*>(HallT) + (size_t)(t + 1) * 65536,
            reinterpret_cast<const short8*>(Wfe) + (size_t)cg_ * 8192,
            reinterpret_cast<short8*>(Wlds), acc);

  const int tid = threadIdx.x, lane = tid & 63, wave = tid >> 6;
  const int l15 = lane & 15, l4 = lane >> 4;
  const int rw = wave * 32;
#pragma unroll
  for (int rt = 0; rt < 2; ++rt)
#pragma unroll
    for (int ct = 0; ct < 2; ++ct) {
      const int col = cg_ * 32 + ct * 16 + l15;
      const float bias = b_fe[col];
#pragma unroll
      for (int r = 0; r < 4; ++r) {
        const int row = rw + rt * 16 + l4 * 4 + r;
        fe[((size_t)t * 256 + row) * 128 + col] = acc[rt][ct][r] + bias;
      }
    }
}

// z = eps*softplus(fe[:,64:]-5) + fe[:,:64]; outputs laid out (B,K,T)
__global__ void z_kernel(const float* __restrict__ eps, const float* __restrict__ fe,
                         float* __restrict__ out) {
  const int tid = blockIdx.x * blockDim.x + threadIdx.x;  // 524288 = T*B*K
  const int tt = tid >> 14;
  const int b = (tid >> 6) & 255;
  const int k = tid & 63;
  const int frow = tt * 256 + b;
  const float mus = fe[frow * 128 + k];
  const float sig = softplusf_(fe[frow * 128 + 64 + k] - 5.0f);
  const float z = eps[tid] * sig + mus;
  const int o = (b * KK + k) * TT + tt;
  out[o] = z;
  out[524288 + o] = mus;
  out[2 * 524288 + o] = sig;
}

extern "C" void kernel_launch(void* const* d_in, const int* in_sizes, int n_in,
                              void* d_out, int out_size, void* d_ws, size_t ws_size,
                              hipStream_t stream) {
  const float* x    = (const float*)d_in[0];
  const float* eps  = (const float*)d_in[1];
  const float* W_ih = (const float*)d_in[2];
  const float* W_hh = (const float*)d_in[3];
  const float* b_ih = (const float*)d_in[4];
  const float* b_hh = (const float*)d_in[5];
  const float* W_fe = (const float*)d_in[6];
  const float* b_fe = (const float*)d_in[7];
  float* out = (float*)d_out;

  const size_t BH  = (size_t)BB * HH;       // 524288
  const size_t BKT = (size_t)BB * KK * TT;  // 524288

  char* p = (char*)d_ws;
  auto nxt = [&](size_t bytes) -> char* {
    char* r = p; p += (bytes + 255) & ~(size_t)255; return r;
  };
  unsigned short* Wbig  = (unsigned short*)nxt((size_t)G4 * HH * 2);       // 32 MB, W_ih then W_hh
  float*          xg    = (float*)nxt((size_t)BB * G4 * 4);                // 8 MB
  unsigned short* HallT = (unsigned short*)nxt((size_t)(TT + 1) * BH * 2); // 33 MB
  unsigned short* XT    = (unsigned short*)nxt(BH * 2);                    // 1 MB
  unsigned short* Wfeb  = (unsigned short*)nxt((size_t)128 * HH * 2);      // 0.5 MB
  float*          fe    = (float*)nxt((size_t)(TT * BB) * 128 * 4);        // 4 MB
  unsigned int*   bar   = (unsigned int*)nxt(256);                         // grid barrier

  hipMemsetAsync(bar, 0, 256, stream);

  cvt_x_kernel<<<256, 256, 0, stream>>>(x, XT);
  cvt_w_kernel<0><<<64, 256, 0, stream>>>(W_fe, Wfeb, 16384);
  cvt_w_kernel<1><<<4096, 256, 0, stream>>>(W_ih, Wbig, 1048576);
  xg_kernel<<<256, 512, 0, stream>>>(XT, Wbig, b_ih, b_hh, xg);
  cvt_w_kernel<1><<<4096, 256, 0, stream>>>(W_hh, Wbig, 1048576);

  lstm_loop_kernel<<<256, 1024, 0, stream>>>(
      HallT, Wbig, xg, out + 3 * BKT, out + 3 * BKT + BH, bar);

  fe_kernel<<<128, 512, 0, stream>>>(HallT, Wfeb, b_fe, fe);
  z_kernel<<<2048, 256, 0, stream>>>(eps, fe, out);
}